// Round 5
// baseline (97.396 us; speedup 1.0000x reference)
//
#include <hip/hip_runtime.h>
#include <hip/hip_bf16.h>

#define LAMBDA 0.75f
#define CMID 256
#define DOUT 4096

typedef __attribute__((ext_vector_type(8))) short bf16x8;   // MFMA A/B operand
typedef __attribute__((ext_vector_type(4))) float f32x4;    // MFMA C/D operand

static inline __device__ short f2bf(float f) {
    __hip_bfloat16 h = __float2bfloat16(f);
    short s; __builtin_memcpy(&s, &h, 2);
    return s;
}
static inline __device__ unsigned pack2(float lo, float hi) {
    unsigned a = (unsigned short)f2bf(lo);
    unsigned b = (unsigned short)f2bf(hi);
    return a | (b << 16);
}

// ---------------------------------------------------------------------------
// Fused conv3x3(p=1)+bias+relu+hardshrink+pool, implicit GEMM via MFMA.
// Block = (b, out-row pair h0,h0+1). 256 columns (2 rows x 128 px).
// Phase 1: stage raw x f32 (3ci x 4rows x 136cols, zero-padded) into LDS.
// Phase 2: build bf16 im2col ONCE per block: thread t owns column t,
//          writes 32 k-slots (27 live, 5 zeroed) as 4x ds_write_b128.
//          Column stride 20 dwords (80B) -> <=2-way bank alias on b128 reads.
// Phase 3: wave wv owns co [64wv, 64wv+64). Per px-tile: ONE ds_read_b128
//          gives the A-frag (X, rows=px); weights are the B-frag (cols=co,
//          held in VGPRs). D[px,co]: col=lane&15=co -> pool reduce is 3
//          in-lane adds + shfl_xor(16)+shfl_xor(32) per co-tile.
// k-slot map s=g*8+j: g<3: ci=g, ky=j/3, kx=j%3 ; s=24+j (j<3): ci=j, tap(2,2);
// s>=27 zero. Same map on A and B => any HW k=sigma(g,j) bijection works.
// ---------------------------------------------------------------------------
__global__ __launch_bounds__(256, 4) void conv_pool_mfma(
    const float* __restrict__ x, const float* __restrict__ conv_w,
    const float* __restrict__ conv_b, float* __restrict__ pooled)
{
    __shared__ float    raw[3 * 4 * 136];     // [ci][r 0..3][idx], col = idx-4
    __shared__ unsigned im2col[256 * 20];     // [col][16 bf16-pairs + 4 pad]

    const int b  = blockIdx.x >> 6;
    const int h0 = (blockIdx.x & 63) * 2;
    const int t  = threadIdx.x;
    const int l  = t & 63;
    const int wv = t >> 6;
    const int lm = l & 15;
    const int g  = l >> 4;

    // ---- phase 1: stage raw x (zero-padded borders) ----
    for (int i = t; i < 1632; i += 256) {
        int ci  = i / 544;
        int rem = i - ci * 544;
        int r   = rem / 136;
        int idx = rem - r * 136;
        int hh  = h0 - 1 + r;
        int col = idx - 4;
        float v = 0.f;
        if ((unsigned)hh < 128u && (unsigned)col < 128u)
            v = x[(b * 3 + ci) * 16384 + hh * 128 + col];
        raw[i] = v;
    }

    // ---- weights as B-frags (col n = lm -> co), bias, pool init ----
    bf16x8 wfrag[4];
    f32x4  biasf[4], pool[4];
    #pragma unroll
    for (int c = 0; c < 4; ++c) {
        const int ct = wv * 4 + c;
        const int co = ct * 16 + lm;
        const float* wp = conv_w + co * 27;
        float av[8];
        if (g < 3) {
            #pragma unroll
            for (int j = 0; j < 8; ++j) av[j] = wp[g * 9 + j];
        } else {
            av[0] = wp[8]; av[1] = wp[17]; av[2] = wp[26];
            av[3] = av[4] = av[5] = av[6] = av[7] = 0.f;
        }
        #pragma unroll
        for (int j = 0; j < 8; ++j) wfrag[c][j] = f2bf(av[j]);
        const float bb = conv_b[co];
        biasf[c] = (f32x4){bb, bb, bb, bb};
        pool[c]  = (f32x4){0.f, 0.f, 0.f, 0.f};
    }

    __syncthreads();

    // ---- phase 2: build im2col, thread t = column (out_r = t>>7, px = t&127) ----
    {
        const int out_r = t >> 7;
        const int px    = t & 127;
        unsigned q[16];
        #pragma unroll
        for (int ci = 0; ci < 3; ++ci) {
            const float* rp = raw + ci * 544 + out_r * 136 + px + 3; // (ky,kx)->rp[ky*136+kx]
            q[ci * 4 + 0] = pack2(rp[0],   rp[1]);     // (0,0) (0,1)
            q[ci * 4 + 1] = pack2(rp[2],   rp[136]);   // (0,2) (1,0)
            q[ci * 4 + 2] = pack2(rp[137], rp[138]);   // (1,1) (1,2)
            q[ci * 4 + 3] = pack2(rp[272], rp[273]);   // (2,0) (2,1)
        }
        const float t8c0 = raw[0 * 544 + out_r * 136 + px + 3 + 274]; // (2,2) ci0
        const float t8c1 = raw[1 * 544 + out_r * 136 + px + 3 + 274];
        const float t8c2 = raw[2 * 544 + out_r * 136 + px + 3 + 274];
        q[12] = pack2(t8c0, t8c1);     // s24, s25
        q[13] = pack2(t8c2, 0.f);      // s26, s27(dead=0)
        q[14] = 0u; q[15] = 0u;        // s28..s31 dead = 0 (avoid NaN*0)
        unsigned* dst = &im2col[t * 20];
        #pragma unroll
        for (int q4 = 0; q4 < 4; ++q4)
            *(uint4*)(dst + q4 * 4) = *(const uint4*)(q + q4 * 4);
    }

    __syncthreads();

    // ---- phase 3: 16 px-tiles x 4 co-tiles ----
    #pragma unroll
    for (int tile = 0; tile < 16; ++tile) {
        const uint4 xr = *(const uint4*)&im2col[(tile * 16 + lm) * 20 + g * 4];
        bf16x8 xf; __builtin_memcpy(&xf, &xr, 16);
        #pragma unroll
        for (int c = 0; c < 4; ++c) {
            f32x4 acc = __builtin_amdgcn_mfma_f32_16x16x32_bf16(
                xf, wfrag[c], biasf[c], 0, 0, 0);
            #pragma unroll
            for (int r = 0; r < 4; ++r)
                pool[c][r] += (acc[r] > LAMBDA) ? acc[r] : 0.f; // relu+hardshrink
        }
    }

    // ---- reduce over px (rows): in-lane fold + xor16 + xor32 ----
    #pragma unroll
    for (int c = 0; c < 4; ++c) {
        float s = (pool[c][0] + pool[c][1]) + (pool[c][2] + pool[c][3]);
        s += __shfl_xor(s, 16, 64);
        s += __shfl_xor(s, 32, 64);
        if (l < 16)
            atomicAdd(&pooled[b * CMID + (wv * 4 + c) * 16 + lm], s);
    }
}

// ---------------------------------------------------------------------------
// FC: out[b][d] = log_sigmoid(dot(pooled[b]/16384, fc_w[d]) + fc_b[d])
// ---------------------------------------------------------------------------
__global__ __launch_bounds__(256) void fc_kernel(
    const float* __restrict__ pooled, const float* __restrict__ fc_w,
    const float* __restrict__ fc_b, float* __restrict__ out)
{
    __shared__ float pool[CMID];
    const int b = blockIdx.y;
    const int t = threadIdx.x;
    pool[t] = pooled[b * CMID + t] * (1.0f / 16384.0f);
    __syncthreads();

    const int d = blockIdx.x * 256 + t;
    const float4* wrow = (const float4*)(fc_w + d * CMID);
    float acc = fc_b[d];
    #pragma unroll 8
    for (int k4 = 0; k4 < CMID / 4; k4++) {
        float4 wv = wrow[k4];
        acc += wv.x * pool[k4 * 4 + 0] + wv.y * pool[k4 * 4 + 1]
             + wv.z * pool[k4 * 4 + 2] + wv.w * pool[k4 * 4 + 3];
    }
    float ls = fminf(acc, 0.f) - log1pf(expf(-fabsf(acc)));
    out[b * (int)DOUT + d] = ls;
}

// ---------------------------------------------------------------------------
extern "C" void kernel_launch(void* const* d_in, const int* in_sizes, int n_in,
                              void* d_out, int out_size, void* d_ws, size_t ws_size,
                              hipStream_t stream) {
    const float* x      = (const float*)d_in[0];   // [32,3,128,128]
    const float* conv_w = (const float*)d_in[1];   // [256,3,3,3]
    const float* conv_b = (const float*)d_in[2];   // [256]
    const float* fc_w   = (const float*)d_in[3];   // [4096,256]
    const float* fc_b   = (const float*)d_in[4];   // [4096]
    float* out = (float*)d_out;                    // [32,4096]

    float* pooled = (float*)d_ws;                  // 32*256 floats = 32 KB

    hipMemsetAsync(pooled, 0, 32 * CMID * sizeof(float), stream);
    conv_pool_mfma<<<32 * 64, 256, 0, stream>>>(x, conv_w, conv_b, pooled);
    fc_kernel<<<dim3(16, 32), 256, 0, stream>>>(pooled, fc_w, fc_b, out);
}

// Round 6
// 51.722 us; speedup vs baseline: 1.8831x; 1.8831x over previous
//
#include <hip/hip_runtime.h>
#include <hip/hip_bf16.h>

#define LAMBDA 0.75f
#define CMID 256
#define DOUT 4096

typedef __attribute__((ext_vector_type(8))) short bf16x8;   // MFMA A/B operand
typedef __attribute__((ext_vector_type(4))) float f32x4;    // MFMA C/D operand

static inline __device__ short f2bf(float f) {
    __hip_bfloat16 h = __float2bfloat16(f);
    short s; __builtin_memcpy(&s, &h, 2);
    return s;
}
static inline __device__ unsigned pack2(float lo, float hi) {
    unsigned a = (unsigned short)f2bf(lo);
    unsigned b = (unsigned short)f2bf(hi);
    return a | (b << 16);
}

// ---------------------------------------------------------------------------
// Fused conv3x3(p=1)+bias+relu+hardshrink+pool, implicit GEMM via MFMA.
// Block = (b, out-row pair h0,h0+1). 256 columns (2 rows x 128 px).
// Phase 1: stage raw x f32 (3ci x 4rows x 136cols, zero-padded) into LDS.
// Phase 2: build bf16 im2col ONCE per block: thread t owns column t,
//          writes 32 k-slots (27 live, 5 zeroed) as 4x ds_write_b128.
// Phase 3: wave wv owns co [64wv, 64wv+64). Per px-tile: ONE ds_read_b128
//          gives the A-frag (X, rows=px); weights are B-frag in VGPRs.
//          D[px,co]: col=lane&15=co -> pool reduce is 3 in-lane adds +
//          shfl_xor(16)+shfl_xor(32) per co-tile.
// k-slot map s=g*8+j identical on A and B sides (any HW bijection works).
// NOTE round-5 lesson: launch_bounds(256,4) capped VGPR at 64 -> ~300MB of
// scratch spill traffic. (256,2) gives 128 VGPRs, zero spill, 2 blocks/CU.
// ---------------------------------------------------------------------------
__global__ __launch_bounds__(256, 2) void conv_pool_mfma(
    const float* __restrict__ x, const float* __restrict__ conv_w,
    const float* __restrict__ conv_b, float* __restrict__ pooled)
{
    __shared__ float    raw[3 * 4 * 136];     // [ci][r 0..3][idx], col = idx-4
    __shared__ unsigned im2col[256 * 20];     // [col][16 bf16-pairs + 4 pad]

    const int b  = blockIdx.x >> 6;
    const int h0 = (blockIdx.x & 63) * 2;
    const int t  = threadIdx.x;
    const int l  = t & 63;
    const int wv = t >> 6;
    const int lm = l & 15;
    const int g  = l >> 4;

    // ---- phase 1: stage raw x (zero-padded borders) ----
    for (int i = t; i < 1632; i += 256) {
        int ci  = i / 544;
        int rem = i - ci * 544;
        int r   = rem / 136;
        int idx = rem - r * 136;
        int hh  = h0 - 1 + r;
        int col = idx - 4;
        float v = 0.f;
        if ((unsigned)hh < 128u && (unsigned)col < 128u)
            v = x[(b * 3 + ci) * 16384 + hh * 128 + col];
        raw[i] = v;
    }

    // ---- weights as B-frags (col n = lm -> co), bias, pool init ----
    bf16x8 wfrag[4];
    f32x4  biasf[4], pool[4];
    #pragma unroll
    for (int c = 0; c < 4; ++c) {
        const int ct = wv * 4 + c;
        const int co = ct * 16 + lm;
        const float* wp = conv_w + co * 27;
        float av[8];
        if (g < 3) {
            #pragma unroll
            for (int j = 0; j < 8; ++j) av[j] = wp[g * 9 + j];
        } else {
            av[0] = wp[8]; av[1] = wp[17]; av[2] = wp[26];
            av[3] = av[4] = av[5] = av[6] = av[7] = 0.f;
        }
        #pragma unroll
        for (int j = 0; j < 8; ++j) wfrag[c][j] = f2bf(av[j]);
        const float bb = conv_b[co];
        biasf[c] = (f32x4){bb, bb, bb, bb};
        pool[c]  = (f32x4){0.f, 0.f, 0.f, 0.f};
    }

    __syncthreads();

    // ---- phase 2: build im2col, thread t = column (out_r = t>>7, px = t&127) ----
    {
        const int out_r = t >> 7;
        const int px    = t & 127;
        unsigned* dst = &im2col[t * 20];
        const float* r0 = raw + 0 * 544 + out_r * 136 + px + 3;
        const float* r1 = raw + 1 * 544 + out_r * 136 + px + 3;
        const float* r2 = raw + 2 * 544 + out_r * 136 + px + 3;
        // build + write each uint4 immediately (keeps peak VGPR pressure low)
        uint4 w;
        w.x = pack2(r0[0],   r0[1]);   w.y = pack2(r0[2],   r0[136]);
        w.z = pack2(r0[137], r0[138]); w.w = pack2(r0[272], r0[273]);
        *(uint4*)(dst + 0) = w;
        w.x = pack2(r1[0],   r1[1]);   w.y = pack2(r1[2],   r1[136]);
        w.z = pack2(r1[137], r1[138]); w.w = pack2(r1[272], r1[273]);
        *(uint4*)(dst + 4) = w;
        w.x = pack2(r2[0],   r2[1]);   w.y = pack2(r2[2],   r2[136]);
        w.z = pack2(r2[137], r2[138]); w.w = pack2(r2[272], r2[273]);
        *(uint4*)(dst + 8) = w;
        w.x = pack2(r0[274], r1[274]); w.y = pack2(r2[274], 0.f);
        w.z = 0u;                      w.w = 0u;   // dead k-slots = 0
        *(uint4*)(dst + 12) = w;
    }

    __syncthreads();

    // ---- phase 3: 16 px-tiles x 4 co-tiles ----
    #pragma unroll
    for (int tile = 0; tile < 16; ++tile) {
        const uint4 xr = *(const uint4*)&im2col[(tile * 16 + lm) * 20 + g * 4];
        bf16x8 xf; __builtin_memcpy(&xf, &xr, 16);
        #pragma unroll
        for (int c = 0; c < 4; ++c) {
            f32x4 acc = __builtin_amdgcn_mfma_f32_16x16x32_bf16(
                xf, wfrag[c], biasf[c], 0, 0, 0);
            #pragma unroll
            for (int r = 0; r < 4; ++r)
                pool[c][r] += (acc[r] > LAMBDA) ? acc[r] : 0.f; // relu+hardshrink
        }
    }

    // ---- reduce over px (rows): in-lane fold + xor16 + xor32 ----
    #pragma unroll
    for (int c = 0; c < 4; ++c) {
        float s = (pool[c][0] + pool[c][1]) + (pool[c][2] + pool[c][3]);
        s += __shfl_xor(s, 16, 64);
        s += __shfl_xor(s, 32, 64);
        if (l < 16)
            atomicAdd(&pooled[b * CMID + (wv * 4 + c) * 16 + lm], s);
    }
}

// ---------------------------------------------------------------------------
// FC: out[b][d] = log_sigmoid(dot(pooled[b]/16384, fc_w[d]) + fc_b[d])
// ---------------------------------------------------------------------------
__global__ __launch_bounds__(256) void fc_kernel(
    const float* __restrict__ pooled, const float* __restrict__ fc_w,
    const float* __restrict__ fc_b, float* __restrict__ out)
{
    __shared__ float pool[CMID];
    const int b = blockIdx.y;
    const int t = threadIdx.x;
    pool[t] = pooled[b * CMID + t] * (1.0f / 16384.0f);
    __syncthreads();

    const int d = blockIdx.x * 256 + t;
    const float4* wrow = (const float4*)(fc_w + d * CMID);
    float acc = fc_b[d];
    #pragma unroll 8
    for (int k4 = 0; k4 < CMID / 4; k4++) {
        float4 wv = wrow[k4];
        acc += wv.x * pool[k4 * 4 + 0] + wv.y * pool[k4 * 4 + 1]
             + wv.z * pool[k4 * 4 + 2] + wv.w * pool[k4 * 4 + 3];
    }
    float ls = fminf(acc, 0.f) - log1pf(expf(-fabsf(acc)));
    out[b * (int)DOUT + d] = ls;
}

// ---------------------------------------------------------------------------
extern "C" void kernel_launch(void* const* d_in, const int* in_sizes, int n_in,
                              void* d_out, int out_size, void* d_ws, size_t ws_size,
                              hipStream_t stream) {
    const float* x      = (const float*)d_in[0];   // [32,3,128,128]
    const float* conv_w = (const float*)d_in[1];   // [256,3,3,3]
    const float* conv_b = (const float*)d_in[2];   // [256]
    const float* fc_w   = (const float*)d_in[3];   // [4096,256]
    const float* fc_b   = (const float*)d_in[4];   // [4096]
    float* out = (float*)d_out;                    // [32,4096]

    float* pooled = (float*)d_ws;                  // 32*256 floats = 32 KB

    hipMemsetAsync(pooled, 0, 32 * CMID * sizeof(float), stream);
    conv_pool_mfma<<<32 * 64, 256, 0, stream>>>(x, conv_w, conv_b, pooled);
    fc_kernel<<<dim3(16, 32), 256, 0, stream>>>(pooled, fc_w, fc_b, out);
}

// Round 7
// 51.661 us; speedup vs baseline: 1.8853x; 1.0012x over previous
//
#include <hip/hip_runtime.h>
#include <hip/hip_bf16.h>

#define LAMBDA 0.75f
#define CMID 256
#define DOUT 4096

typedef __attribute__((ext_vector_type(8))) short bf16x8;   // MFMA A/B operand
typedef __attribute__((ext_vector_type(4))) float f32x4;    // MFMA C/D operand

static inline __device__ short f2bf(float f) {
    __hip_bfloat16 h = __float2bfloat16(f);
    short s; __builtin_memcpy(&s, &h, 2);
    return s;
}
static inline __device__ unsigned pack2(float lo, float hi) {
    unsigned a = (unsigned short)f2bf(lo);
    unsigned b = (unsigned short)f2bf(hi);
    return a | (b << 16);
}

// ---------------------------------------------------------------------------
// Fused conv3x3(p=1)+bias+relu+hardshrink+pool, implicit GEMM via MFMA.
// Block = (b, out-row pair). Phase 1: stage raw x f32 (zero-padded) in LDS.
// Phase 2: build bf16 im2col once per block, layout [g][col][16B]:
//          thread t = column t writes 4x uint4, one per k-group g; lane-
//          consecutive columns -> 16B-stride -> conflict-free, 16B-aligned.
// Phase 3: wave wv owns co [64wv,64wv+64). Per px-tile ONE ds_read_b128
//          (quarter-wave reads 256 contiguous bytes of its g-region) feeds
//          4 MFMAs. D[px,co]: col=lane&15=co; fused relu+hardshrink+pool.
// Output: per-block partials part[bk][256] (plain stores -> no memset/atomic).
// k-slot map s=g*8+j identical on A and B sides (any HW bijection works):
//   g<3: ci=g, ky=j/3, kx=j%3 ; g==3: j<3 -> ci=j tap(2,2), j>=3 zero.
// Round-5 lesson: launch_bounds(256,4) forced 64 VGPR -> 300MB spill traffic.
// (256,2) = 128 VGPR, no spill, 4 blocks/CU (LDS 22.4KB would allow 6).
// ---------------------------------------------------------------------------
__global__ __launch_bounds__(256, 2) void conv_pool_mfma(
    const float* __restrict__ x, const float* __restrict__ conv_w,
    const float* __restrict__ conv_b, float* __restrict__ part)
{
    __shared__ float raw[1632];           // [ci][r 0..3][idx 0..135], col=idx-4
    __shared__ uint4 im2col[4][256];      // [g][col] -> 8 bf16 k-slots

    const int bk = blockIdx.x;
    const int b  = bk >> 6;
    const int h0 = (bk & 63) * 2;
    const int t  = threadIdx.x;
    const int l  = t & 63;
    const int wv = t >> 6;
    const int lm = l & 15;
    const int g  = l >> 4;

    // ---- phase 1: stage raw x (zero-padded borders) ----
    for (int i = t; i < 1632; i += 256) {
        int ci  = i / 544;
        int rem = i - ci * 544;
        int r   = rem / 136;
        int idx = rem - r * 136;
        int hh  = h0 - 1 + r;
        int col = idx - 4;
        float v = 0.f;
        if ((unsigned)hh < 128u && (unsigned)col < 128u)
            v = x[(b * 3 + ci) * 16384 + hh * 128 + col];
        raw[i] = v;
    }

    // ---- weights as B-frags (col n = lm -> co), bias, pool init ----
    bf16x8 wfrag[4];
    f32x4  biasf[4], pool[4];
    #pragma unroll
    for (int c = 0; c < 4; ++c) {
        const int ct = wv * 4 + c;
        const int co = ct * 16 + lm;
        const float* wp = conv_w + co * 27;
        float av[8];
        if (g < 3) {
            #pragma unroll
            for (int j = 0; j < 8; ++j) av[j] = wp[g * 9 + j];
        } else {
            av[0] = wp[8]; av[1] = wp[17]; av[2] = wp[26];
            av[3] = av[4] = av[5] = av[6] = av[7] = 0.f;
        }
        #pragma unroll
        for (int j = 0; j < 8; ++j) wfrag[c][j] = f2bf(av[j]);
        const float bb = conv_b[co];
        biasf[c] = (f32x4){bb, bb, bb, bb};
        pool[c]  = (f32x4){0.f, 0.f, 0.f, 0.f};
    }

    __syncthreads();

    // ---- phase 2: build im2col, thread t = column (out_r = t>>7, px = t&127) ----
    {
        const int out_r = t >> 7;
        const int px    = t & 127;
        const float* r0 = raw + 0 * 544 + out_r * 136 + px + 3;
        const float* r1 = raw + 1 * 544 + out_r * 136 + px + 3;
        const float* r2 = raw + 2 * 544 + out_r * 136 + px + 3;
        uint4 w;
        w.x = pack2(r0[0],   r0[1]);   w.y = pack2(r0[2],   r0[136]);
        w.z = pack2(r0[137], r0[138]); w.w = pack2(r0[272], r0[273]);
        im2col[0][t] = w;
        w.x = pack2(r1[0],   r1[1]);   w.y = pack2(r1[2],   r1[136]);
        w.z = pack2(r1[137], r1[138]); w.w = pack2(r1[272], r1[273]);
        im2col[1][t] = w;
        w.x = pack2(r2[0],   r2[1]);   w.y = pack2(r2[2],   r2[136]);
        w.z = pack2(r2[137], r2[138]); w.w = pack2(r2[272], r2[273]);
        im2col[2][t] = w;
        w.x = pack2(r0[274], r1[274]); w.y = pack2(r2[274], 0.f);
        w.z = 0u;                      w.w = 0u;   // dead k-slots = 0
        im2col[3][t] = w;
    }

    __syncthreads();

    // ---- phase 3: 16 px-tiles x 4 co-tiles ----
    #pragma unroll
    for (int tile = 0; tile < 16; ++tile) {
        const uint4 xr = im2col[g][tile * 16 + lm];   // conflict-free b128
        bf16x8 xf; __builtin_memcpy(&xf, &xr, 16);
        #pragma unroll
        for (int c = 0; c < 4; ++c) {
            f32x4 acc = __builtin_amdgcn_mfma_f32_16x16x32_bf16(
                xf, wfrag[c], biasf[c], 0, 0, 0);
            #pragma unroll
            for (int r = 0; r < 4; ++r)
                pool[c][r] += (acc[r] > LAMBDA) ? acc[r] : 0.f; // relu+hardshrink
        }
    }

    // ---- reduce over px: in-lane fold + xor16 + xor32; plain partial store ----
    #pragma unroll
    for (int c = 0; c < 4; ++c) {
        float s = (pool[c][0] + pool[c][1]) + (pool[c][2] + pool[c][3]);
        s += __shfl_xor(s, 16, 64);
        s += __shfl_xor(s, 32, 64);
        if (l < 16)
            part[bk * 256 + wv * 64 + c * 16 + lm] = s;
    }
}

// ---------------------------------------------------------------------------
// FC: reduce 64 per-block partials -> pooled[b], then
// out[b][d] = log_sigmoid(dot(pooled[b]/16384, fc_w[d]) + fc_b[d])
// ---------------------------------------------------------------------------
__global__ __launch_bounds__(256) void fc_kernel(
    const float* __restrict__ part, const float* __restrict__ fc_w,
    const float* __restrict__ fc_b, float* __restrict__ out)
{
    __shared__ float pool[CMID];
    const int b = blockIdx.y;
    const int t = threadIdx.x;

    // sum the 64 row-block partials for this batch (coalesced, L2-hot)
    float s = 0.f;
    const float* pp = part + b * 64 * 256 + t;
    #pragma unroll
    for (int j = 0; j < 64; ++j) s += pp[j * 256];
    pool[t] = s * (1.0f / 16384.0f);
    __syncthreads();

    const int d = blockIdx.x * 256 + t;
    const float4* wrow = (const float4*)(fc_w + d * CMID);
    float acc = fc_b[d];
    #pragma unroll 8
    for (int k4 = 0; k4 < CMID / 4; k4++) {
        float4 wv = wrow[k4];
        acc += wv.x * pool[k4 * 4 + 0] + wv.y * pool[k4 * 4 + 1]
             + wv.z * pool[k4 * 4 + 2] + wv.w * pool[k4 * 4 + 3];
    }
    float ls = fminf(acc, 0.f) - log1pf(expf(-fabsf(acc)));
    out[b * (int)DOUT + d] = ls;
}

// ---------------------------------------------------------------------------
extern "C" void kernel_launch(void* const* d_in, const int* in_sizes, int n_in,
                              void* d_out, int out_size, void* d_ws, size_t ws_size,
                              hipStream_t stream) {
    const float* x      = (const float*)d_in[0];   // [32,3,128,128]
    const float* conv_w = (const float*)d_in[1];   // [256,3,3,3]
    const float* conv_b = (const float*)d_in[2];   // [256]
    const float* fc_w   = (const float*)d_in[3];   // [4096,256]
    const float* fc_b   = (const float*)d_in[4];   // [4096]
    float* out = (float*)d_out;                    // [32,4096]

    float* part = (float*)d_ws;                    // [2048][256] = 2 MB partials

    conv_pool_mfma<<<32 * 64, 256, 0, stream>>>(x, conv_w, conv_b, part);
    fc_kernel<<<dim3(16, 32), 256, 0, stream>>>(part, fc_w, fc_b, out);
}

// Round 8
// 51.234 us; speedup vs baseline: 1.9010x; 1.0083x over previous
//
#include <hip/hip_runtime.h>
#include <hip/hip_bf16.h>

#define LAMBDA 0.75f
#define CMID 256
#define DOUT 4096

typedef __attribute__((ext_vector_type(8))) short bf16x8;   // MFMA A/B operand
typedef __attribute__((ext_vector_type(4))) float f32x4;    // MFMA C/D operand

static inline __device__ short f2bf(float f) {
    __hip_bfloat16 h = __float2bfloat16(f);
    short s; __builtin_memcpy(&s, &h, 2);
    return s;
}
static inline __device__ unsigned pack2(float lo, float hi) {
    unsigned a = (unsigned short)f2bf(lo);
    unsigned b = (unsigned short)f2bf(hi);
    return a | (b << 16);
}

// ---------------------------------------------------------------------------
// Fused conv3x3(p=1)+bias+relu+hardshrink+pool, implicit GEMM via MFMA.
// Round-8 change: phase 3 is an explicit 1-deep software pipeline --
//   prefetch x(t+1) [ds_read] -> issue 4 MFMAs for tile t -> epilogue of
//   tile t-1 (48 VALU hides ds + MFMA latency) -> rotate (named regs only).
// Rounds 6/7 plateaued at ~50us total vs ~7us issue model: the unpipelined
// loop exposed ~120cyc ds latency + MFMA->VALU latency on every tile.
// Layout recap: im2col[g][col] uint4 (conflict-free b128); k-slot map
// s=g*8+j identical on A and B sides; per-block partials (no atomics).
// launch_bounds(256,2)=128 VGPR: hand-count ~107 live -> no spill (r5 lesson).
// ---------------------------------------------------------------------------
__global__ __launch_bounds__(256, 2) void conv_pool_mfma(
    const float* __restrict__ x, const float* __restrict__ conv_w,
    const float* __restrict__ conv_b, float* __restrict__ part)
{
    __shared__ float raw[1632];           // [ci][r 0..3][idx 0..135], col=idx-4
    __shared__ uint4 im2col[4][256];      // [g][col] -> 8 bf16 k-slots

    const int bk = blockIdx.x;
    const int b  = bk >> 6;
    const int h0 = (bk & 63) * 2;
    const int t  = threadIdx.x;
    const int l  = t & 63;
    const int wv = t >> 6;
    const int lm = l & 15;
    const int g  = l >> 4;

    // ---- phase 1: stage raw x (zero-padded borders), coalesced ----
    for (int i = t; i < 1632; i += 256) {
        int ci  = i / 544;
        int rem = i - ci * 544;
        int r   = rem / 136;
        int idx = rem - r * 136;
        int hh  = h0 - 1 + r;
        int col = idx - 4;
        float v = 0.f;
        if ((unsigned)hh < 128u && (unsigned)col < 128u)
            v = x[(b * 3 + ci) * 16384 + hh * 128 + col];
        raw[i] = v;
    }

    // ---- weights as B-frags (col n = lm -> co), bias, pool init ----
    bf16x8 wfrag[4];
    f32x4  biasf[4], pool[4];
    #pragma unroll
    for (int c = 0; c < 4; ++c) {
        const int ct = wv * 4 + c;
        const int co = ct * 16 + lm;
        const float* wp = conv_w + co * 27;
        float av[8];
        if (g < 3) {
            #pragma unroll
            for (int j = 0; j < 8; ++j) av[j] = wp[g * 9 + j];
        } else {
            av[0] = wp[8]; av[1] = wp[17]; av[2] = wp[26];
            av[3] = av[4] = av[5] = av[6] = av[7] = 0.f;
        }
        #pragma unroll
        for (int j = 0; j < 8; ++j) wfrag[c][j] = f2bf(av[j]);
        const float bb = conv_b[co];
        biasf[c] = (f32x4){bb, bb, bb, bb};
        pool[c]  = (f32x4){0.f, 0.f, 0.f, 0.f};
    }

    __syncthreads();

    // ---- phase 2: build im2col, thread t = column (out_r = t>>7, px = t&127) ----
    {
        const int out_r = t >> 7;
        const int px    = t & 127;
        const float* r0 = raw + 0 * 544 + out_r * 136 + px + 3;
        const float* r1 = raw + 1 * 544 + out_r * 136 + px + 3;
        const float* r2 = raw + 2 * 544 + out_r * 136 + px + 3;
        uint4 w;
        w.x = pack2(r0[0],   r0[1]);   w.y = pack2(r0[2],   r0[136]);
        w.z = pack2(r0[137], r0[138]); w.w = pack2(r0[272], r0[273]);
        im2col[0][t] = w;
        w.x = pack2(r1[0],   r1[1]);   w.y = pack2(r1[2],   r1[136]);
        w.z = pack2(r1[137], r1[138]); w.w = pack2(r1[272], r1[273]);
        im2col[1][t] = w;
        w.x = pack2(r2[0],   r2[1]);   w.y = pack2(r2[2],   r2[136]);
        w.z = pack2(r2[137], r2[138]); w.w = pack2(r2[272], r2[273]);
        im2col[2][t] = w;
        w.x = pack2(r0[274], r1[274]); w.y = pack2(r2[274], 0.f);
        w.z = 0u;                      w.w = 0u;   // dead k-slots = 0
        im2col[3][t] = w;
    }

    __syncthreads();

    // ---- phase 3: 16 px-tiles x 4 co-tiles, 1-deep software pipeline ----
    // prologue: tile 0
    f32x4 accP0, accP1, accP2, accP3;     // pending epilogue (named, static)
    uint4 x_nxt;
    {
        const uint4 x0 = im2col[g][lm];
        x_nxt = im2col[g][16 + lm];       // prefetch tile 1
        bf16x8 xf; __builtin_memcpy(&xf, &x0, 16);
        accP0 = __builtin_amdgcn_mfma_f32_16x16x32_bf16(xf, wfrag[0], biasf[0], 0, 0, 0);
        accP1 = __builtin_amdgcn_mfma_f32_16x16x32_bf16(xf, wfrag[1], biasf[1], 0, 0, 0);
        accP2 = __builtin_amdgcn_mfma_f32_16x16x32_bf16(xf, wfrag[2], biasf[2], 0, 0, 0);
        accP3 = __builtin_amdgcn_mfma_f32_16x16x32_bf16(xf, wfrag[3], biasf[3], 0, 0, 0);
    }
    #pragma unroll
    for (int tile = 1; tile < 16; ++tile) {
        bf16x8 xf; __builtin_memcpy(&xf, &x_nxt, 16);
        if (tile < 15) x_nxt = im2col[g][(tile + 1) * 16 + lm];  // prefetch t+1
        // issue MFMAs for tile (independent of accP epilogue below)
        f32x4 accN0 = __builtin_amdgcn_mfma_f32_16x16x32_bf16(xf, wfrag[0], biasf[0], 0, 0, 0);
        f32x4 accN1 = __builtin_amdgcn_mfma_f32_16x16x32_bf16(xf, wfrag[1], biasf[1], 0, 0, 0);
        f32x4 accN2 = __builtin_amdgcn_mfma_f32_16x16x32_bf16(xf, wfrag[2], biasf[2], 0, 0, 0);
        f32x4 accN3 = __builtin_amdgcn_mfma_f32_16x16x32_bf16(xf, wfrag[3], biasf[3], 0, 0, 0);
        // epilogue of tile-1 (hides ds_read + MFMA latency)
        #pragma unroll
        for (int r = 0; r < 4; ++r) {
            pool[0][r] += (accP0[r] > LAMBDA) ? accP0[r] : 0.f;
            pool[1][r] += (accP1[r] > LAMBDA) ? accP1[r] : 0.f;
            pool[2][r] += (accP2[r] > LAMBDA) ? accP2[r] : 0.f;
            pool[3][r] += (accP3[r] > LAMBDA) ? accP3[r] : 0.f;
        }
        accP0 = accN0; accP1 = accN1; accP2 = accN2; accP3 = accN3; // renames
    }
    // drain: epilogue of tile 15
    #pragma unroll
    for (int r = 0; r < 4; ++r) {
        pool[0][r] += (accP0[r] > LAMBDA) ? accP0[r] : 0.f;
        pool[1][r] += (accP1[r] > LAMBDA) ? accP1[r] : 0.f;
        pool[2][r] += (accP2[r] > LAMBDA) ? accP2[r] : 0.f;
        pool[3][r] += (accP3[r] > LAMBDA) ? accP3[r] : 0.f;
    }

    // ---- reduce over px: in-lane fold + xor16 + xor32; plain partial store ----
    #pragma unroll
    for (int c = 0; c < 4; ++c) {
        float s = (pool[c][0] + pool[c][1]) + (pool[c][2] + pool[c][3]);
        s += __shfl_xor(s, 16, 64);
        s += __shfl_xor(s, 32, 64);
        if (l < 16)
            part[bk * 256 + wv * 64 + c * 16 + lm] = s;
    }
}

// ---------------------------------------------------------------------------
// FC: reduce 64 per-block partials -> pooled[b], then
// out[b][d] = log_sigmoid(dot(pooled[b]/16384, fc_w[d]) + fc_b[d])
// ---------------------------------------------------------------------------
__global__ __launch_bounds__(256) void fc_kernel(
    const float* __restrict__ part, const float* __restrict__ fc_w,
    const float* __restrict__ fc_b, float* __restrict__ out)
{
    __shared__ float pool[CMID];
    const int b = blockIdx.y;
    const int t = threadIdx.x;

    float s = 0.f;
    const float* pp = part + b * 64 * 256 + t;
    #pragma unroll
    for (int j = 0; j < 64; ++j) s += pp[j * 256];
    pool[t] = s * (1.0f / 16384.0f);
    __syncthreads();

    const int d = blockIdx.x * 256 + t;
    const float4* wrow = (const float4*)(fc_w + d * CMID);
    float acc = fc_b[d];
    #pragma unroll 8
    for (int k4 = 0; k4 < CMID / 4; k4++) {
        float4 wv = wrow[k4];
        acc += wv.x * pool[k4 * 4 + 0] + wv.y * pool[k4 * 4 + 1]
             + wv.z * pool[k4 * 4 + 2] + wv.w * pool[k4 * 4 + 3];
    }
    float ls = fminf(acc, 0.f) - log1pf(expf(-fabsf(acc)));
    out[b * (int)DOUT + d] = ls;
}

// ---------------------------------------------------------------------------
extern "C" void kernel_launch(void* const* d_in, const int* in_sizes, int n_in,
                              void* d_out, int out_size, void* d_ws, size_t ws_size,
                              hipStream_t stream) {
    const float* x      = (const float*)d_in[0];   // [32,3,128,128]
    const float* conv_w = (const float*)d_in[1];   // [256,3,3,3]
    const float* conv_b = (const float*)d_in[2];   // [256]
    const float* fc_w   = (const float*)d_in[3];   // [4096,256]
    const float* fc_b   = (const float*)d_in[4];   // [4096]
    float* out = (float*)d_out;                    // [32,4096]

    float* part = (float*)d_ws;                    // [2048][256] = 2 MB partials

    conv_pool_mfma<<<32 * 64, 256, 0, stream>>>(x, conv_w, conv_b, part);
    fc_kernel<<<dim3(16, 32), 256, 0, stream>>>(part, fc_w, fc_b, out);
}